// Round 4
// baseline (659.226 us; speedup 1.0000x reference)
//
#include <hip/hip_runtime.h>
#include <hip/hip_bf16.h>
#include <stdint.h>

#define T_SEQ 336
#define NKT   11        // K-steps of 32 (336 -> 352, tail zero-padded)
#define P_LEN 720
#define NM16  48        // 16-row p-blocks (720 -> 768, zero-padded in Apack)
#define C_LEN 1782
#define NB    64
#define CTILE 96
#define NCT   19        // ceil(1782/96)
#define XPITCH 360      // xT row pitch in bf16 elems (720B: 2-way bank alias only)
#define NCHUNK 3        // p-chunks of 256 rows

typedef __attribute__((ext_vector_type(4))) float f32x4;
typedef __attribute__((ext_vector_type(8))) short s16x8;

__device__ __forceinline__ unsigned short f2bf(float f) {
  unsigned int u = __builtin_bit_cast(unsigned int, f);
  u += 0x7FFFu + ((u >> 16) & 1u);   // RNE
  return (unsigned short)(u >> 16);
}

// Weff[p,k] = Ws[p,k] + 0.2*sum_{t in win(k)} (Wt-Ws)[p,t], packed in MFMA
// A-fragment order: block m16*NKT+kt holds 64 lanes x 16B; lane lg*16+l16
// carries W[m16*16+l16][kt*32+lg*8+j], j=0..7. Zero-padded p>=720, k>=336.
__global__ __launch_bounds__(64) void prep_w(
    const float* __restrict__ Ws, const float* __restrict__ bs,
    const float* __restrict__ Wt, const float* __restrict__ bt,
    unsigned short* __restrict__ apack, float* __restrict__ bias) {
  const int p   = blockIdx.x;          // 0..767
  const int tid = threadIdx.x;         // 0..63
  if (tid < NKT * 4) {
    const int kt = tid >> 2;
    const int lg = tid & 3;
    const float* wsr = Ws + (size_t)p * T_SEQ;
    const float* wtr = Wt + (size_t)p * T_SEQ;
    union { s16x8 v; unsigned short u[8]; } pk;
#pragma unroll
    for (int j = 0; j < 8; ++j) {
      const int k = kt * 32 + lg * 8 + j;
      float val = 0.f;
      if (p < P_LEN && k < T_SEQ) {
        float d;
        if (k == 0) {
          d = 3.f*(wtr[0]-wsr[0]) + 2.f*(wtr[1]-wsr[1]) + (wtr[2]-wsr[2]);
        } else if (k == T_SEQ-1) {
          d = 3.f*(wtr[T_SEQ-1]-wsr[T_SEQ-1]) + 2.f*(wtr[T_SEQ-2]-wsr[T_SEQ-2])
              + (wtr[T_SEQ-3]-wsr[T_SEQ-3]);
        } else {
          int lo = (k-2 < 0) ? 0 : k-2;
          int hi = (k+2 > T_SEQ-1) ? T_SEQ-1 : k+2;
          d = 0.f;
          for (int t = lo; t <= hi; ++t) d += wtr[t]-wsr[t];
        }
        val = wsr[k] + 0.2f*d;
      }
      pk.u[j] = f2bf(val);
    }
    const int m16 = p >> 4;
    const int l16 = p & 15;
    *(s16x8*)&apack[(size_t)(((m16*NKT + kt) * 64) + lg*16 + l16) * 8] = pk.v;
  }
  if (tid == 0 && p < P_LEN) bias[p] = bs[p] + bt[p];
}

// O[b,p,c] = relu( sum_k Weff[p,k] * X[b,k,c] + bias[p] )
// Block = (batch b, 96-wide c-slice). X-tile staged ONCE to LDS (bf16),
// single barrier; then 3 p-chunks x 11 K-steps with zero barriers:
// A-frags from packed Weff (coalesced, L2-hot, prefetched), B ds_read_b128.
__global__ __launch_bounds__(512, 4) void gemm_kernel(
    const float* __restrict__ x, const unsigned short* __restrict__ apack,
    const float* __restrict__ bias, float* __restrict__ out) {
  __shared__ unsigned short xT[CTILE * XPITCH];   // [96 c][360 k] bf16, 69120 B

  // spread blocks across XCDs (no inter-block reuse; even distribution only)
  const int bid = blockIdx.x;
  const int w   = (bid & 7) * 152 + (bid >> 3);   // 1216 = 8*152
  const int b   = w / NCT;
  const int ct  = w % NCT;
  const int c0  = ct * CTILE;

  const int tid  = threadIdx.x;
  const int lane = tid & 63;
  const int wid  = tid >> 6;     // 0..7
  const int l16  = lane & 15;
  const int lg   = lane >> 4;

  const float* xb = x + (size_t)b * T_SEQ * C_LEN;

  // ---- zero the k-tail (k 336..351) ----
  if (tid < 384) {
    short4 z = {0, 0, 0, 0};
    *(short4*)&xT[(tid >> 2) * XPITCH + T_SEQ + (tid & 3) * 4] = z;
  }

  // ---- stage X tile: fp32 -> bf16, transposed to [c][k] ----
  for (int pass = 0; pass < 32; ++pass) {
    int idx = pass * 512 + tid;
    if (idx < T_SEQ * 48) {
      int k  = idx / 48;
      int cp = (idx - k * 48) * 2;
      int c  = c0 + cp;
      float2 t; t.x = 0.f; t.y = 0.f;
      if (c < C_LEN) t = *(const float2*)(xb + (size_t)k * C_LEN + c);
      xT[cp * XPITCH + k]       = f2bf(t.x);
      xT[(cp + 1) * XPITCH + k] = f2bf(t.y);
    }
  }
  __syncthreads();   // the only barrier in the kernel

  const s16x8* ap = (const s16x8*)apack;
  const size_t ob = (size_t)b * P_LEN * C_LEN;

  for (int pc = 0; pc < NCHUNK; ++pc) {
    const int m16a = pc * 16 + wid * 2;   // this wave's first 16-row p-block
    f32x4 acc[2][6] = {};

    s16x8 afc[2], afn[2];
#pragma unroll
    for (int m = 0; m < 2; ++m)
      afc[m] = ap[(size_t)((m16a + m) * NKT) * 64 + lane];

#pragma unroll
    for (int kt = 0; kt < NKT; ++kt) {
      if (kt + 1 < NKT) {
#pragma unroll
        for (int m = 0; m < 2; ++m)
          afn[m] = ap[(size_t)((m16a + m) * NKT + kt + 1) * 64 + lane];
      }
      const int ko = kt * 32 + lg * 8;
#pragma unroll
      for (int n = 0; n < 6; ++n) {
        s16x8 bf_ = *(const s16x8*)&xT[(n * 16 + l16) * XPITCH + ko];
        acc[0][n] = __builtin_amdgcn_mfma_f32_16x16x32_bf16(
            afc[0], bf_, acc[0][n], 0, 0, 0);
        acc[1][n] = __builtin_amdgcn_mfma_f32_16x16x32_bf16(
            afc[1], bf_, acc[1][n], 0, 0, 0);
      }
      if (kt + 1 < NKT) { afc[0] = afn[0]; afc[1] = afn[1]; }
    }

    // epilogue (no barrier: stores overlap next chunk's compute)
    // C/D layout: row = lg*4 + r (-> p), col = l16 (-> c)
#pragma unroll
    for (int m = 0; m < 2; ++m) {
      const int m16 = m16a + m;
      if (m16 < 45) {                       // p < 720, uniform per fragment
        const int pb = m16 * 16 + lg * 4;
        float bv[4];
#pragma unroll
        for (int r = 0; r < 4; ++r) bv[r] = bias[pb + r];
#pragma unroll
        for (int n = 0; n < 6; ++n) {
          const int cc = c0 + n * 16 + l16;
          if (cc < C_LEN) {
#pragma unroll
            for (int r = 0; r < 4; ++r) {
              float vv = acc[m][n][r] + bv[r];
              out[ob + (size_t)(pb + r) * C_LEN + cc] = fmaxf(vv, 0.f);
            }
          }
        }
      }
    }
  }
}

extern "C" void kernel_launch(void* const* d_in, const int* in_sizes, int n_in,
                              void* d_out, int out_size, void* d_ws, size_t ws_size,
                              hipStream_t stream) {
  (void)in_sizes; (void)n_in; (void)out_size; (void)ws_size;
  const float* x  = (const float*)d_in[0];
  const float* Ws = (const float*)d_in[1];
  const float* bs = (const float*)d_in[2];
  const float* Wt = (const float*)d_in[3];
  const float* bt = (const float*)d_in[4];
  float* out = (float*)d_out;

  // ws: Apack (48*11 blocks * 1KB = 540672 B) then bias (720 f32)
  unsigned short* apack = (unsigned short*)d_ws;
  float* bias = (float*)((char*)d_ws + (size_t)NM16 * NKT * 1024);

  prep_w<<<dim3(768), dim3(64), 0, stream>>>(Ws, bs, Wt, bt, apack, bias);
  gemm_kernel<<<dim3(NB * NCT), dim3(512), 0, stream>>>(x, apack, bias, out);
}

// Round 5
// 311.292 us; speedup vs baseline: 2.1177x; 2.1177x over previous
//
#include <hip/hip_runtime.h>
#include <hip/hip_bf16.h>
#include <stdint.h>

#define T_SEQ 336
#define NKT   11        // K-steps of 32 (336 -> 352, tail zero-padded)
#define P_LEN 720
#define NM16  48        // 16-row p-blocks (720 -> 768, zero-padded in Apack)
#define C_LEN 1782
#define NB    64
#define BM 128
#define BN 128
#define BK 32
#define XP 40           // xT row pitch (bf16 elems); 80B rows, 16B-aligned

typedef __attribute__((ext_vector_type(4))) float f32x4;
typedef __attribute__((ext_vector_type(8))) short s16x8;

__device__ __forceinline__ unsigned short f2bf(float f) {
  unsigned int u = __builtin_bit_cast(unsigned int, f);
  u += 0x7FFFu + ((u >> 16) & 1u);   // RNE
  return (unsigned short)(u >> 16);
}

// Weff[p,k] = Ws[p,k] + 0.2*sum_{t in win(k)} (Wt-Ws)[p,t], packed in MFMA
// A-fragment order: block m16*NKT+kt holds 64 lanes x 16B; lane lg*16+l16
// carries W[m16*16+l16][kt*32+lg*8+j], j=0..7. Zero-padded p>=720, k>=336.
__global__ __launch_bounds__(64) void prep_w(
    const float* __restrict__ Ws, const float* __restrict__ bs,
    const float* __restrict__ Wt, const float* __restrict__ bt,
    unsigned short* __restrict__ apack, float* __restrict__ bias) {
  const int p   = blockIdx.x;          // 0..767
  const int tid = threadIdx.x;         // 0..63
  if (tid < NKT * 4) {
    const int kt = tid >> 2;
    const int lg = tid & 3;
    const float* wsr = Ws + (size_t)p * T_SEQ;
    const float* wtr = Wt + (size_t)p * T_SEQ;
    union { s16x8 v; unsigned short u[8]; } pk;
#pragma unroll
    for (int j = 0; j < 8; ++j) {
      const int k = kt * 32 + lg * 8 + j;
      float val = 0.f;
      if (p < P_LEN && k < T_SEQ) {
        float d;
        if (k == 0) {
          d = 3.f*(wtr[0]-wsr[0]) + 2.f*(wtr[1]-wsr[1]) + (wtr[2]-wsr[2]);
        } else if (k == T_SEQ-1) {
          d = 3.f*(wtr[T_SEQ-1]-wsr[T_SEQ-1]) + 2.f*(wtr[T_SEQ-2]-wsr[T_SEQ-2])
              + (wtr[T_SEQ-3]-wsr[T_SEQ-3]);
        } else {
          int lo = (k-2 < 0) ? 0 : k-2;
          int hi = (k+2 > T_SEQ-1) ? T_SEQ-1 : k+2;
          d = 0.f;
          for (int t = lo; t <= hi; ++t) d += wtr[t]-wsr[t];
        }
        val = wsr[k] + 0.2f*d;
      }
      pk.u[j] = f2bf(val);
    }
    const int m16 = p >> 4;
    const int l16 = p & 15;
    *(s16x8*)&apack[(size_t)(((m16*NKT + kt) * 64) + lg*16 + l16) * 8] = pk.v;
  }
  if (tid == 0 && p < P_LEN) bias[p] = bs[p] + bt[p];
}

// O[b,p,c] = relu( sum_k Weff[p,k] * X[b,k,c] + bias[p] )
// 128x128 tile, 4 waves (2x2). A-frags: registers, straight from packed Weff
// (1 coalesced dwordx4/lane, L2-hot, double-buffered across K-steps).
// X: reg-prefetch -> cvt_pk -> LDS double-buffer; ONE barrier per K-step:
//   issue loads(t+1) -> MFMA(t) from LDS -> cvt+ds_write(t+1) -> barrier.
__global__ __launch_bounds__(256) void gemm_kernel(
    const float* __restrict__ x, const unsigned short* __restrict__ apack,
    const float* __restrict__ bias, float* __restrict__ out) {
  __shared__ unsigned short xT[2][BN * XP];   // 2 x 10240 B

  // XCD swizzle: each XCD gets 8 consecutive b; within XCD, p-tiles fastest
  const int bid = blockIdx.x;
  const int w   = (bid & 7) * 672 + (bid >> 3);   // 5376 = 8*672, bijective
  const int b   = w / 84;                         // 84 = 14*6 tiles per batch
  const int rem = w % 84;
  const int ct  = rem / 6;
  const int pt  = rem % 6;
  const int p0  = pt * BM;
  const int c0  = ct * BN;

  const int tid  = threadIdx.x;
  const int lane = tid & 63;
  const int wid  = tid >> 6;
  const int wp   = wid >> 1;
  const int wc   = wid & 1;
  const int l16  = lane & 15;
  const int lg   = lane >> 4;

  const float* xb = x + (size_t)b * T_SEQ * C_LEN;
  const s16x8* ap = (const s16x8*)apack;

  // X staging ownership: thread = 2 adjacent c-cols (cpair) x 8 k-rows (kg)
  const int cpair = lane * 2;
  const int kg    = wid;
  const int cg    = c0 + cpair;
  const bool cok  = cg < C_LEN;

  f32x4 acc[4][4] = {};
  s16x8 afc[4];
  float2 v[8];

  // ---- prologue: A(0) + X(0) ----
#pragma unroll
  for (int m = 0; m < 4; ++m)
    afc[m] = ap[(size_t)((pt*8 + wp*4 + m) * NKT) * 64 + lane];
#pragma unroll
  for (int j = 0; j < 8; ++j) {
    int kk = kg * 8 + j;
    float2 t; t.x = 0.f; t.y = 0.f;
    if (cok && kk < T_SEQ) t = *(const float2*)(xb + (size_t)kk * C_LEN + cg);
    v[j] = t;
  }
  {
    union { s16x8 vec; uint32_t dw[4]; } pa, pb;
#pragma unroll
    for (int h = 0; h < 4; ++h) {
      uint32_t ra, rb;
      asm("v_cvt_pk_bf16_f32 %0, %1, %2" : "=v"(ra) : "v"(v[2*h].x), "v"(v[2*h+1].x));
      asm("v_cvt_pk_bf16_f32 %0, %1, %2" : "=v"(rb) : "v"(v[2*h].y), "v"(v[2*h+1].y));
      pa.dw[h] = ra; pb.dw[h] = rb;
    }
    *(s16x8*)&xT[0][cpair * XP + kg * 8]     = pa.vec;
    *(s16x8*)&xT[0][(cpair+1) * XP + kg * 8] = pb.vec;
  }
  __syncthreads();

  // ---- main loop: one barrier per K-step ----
#pragma unroll 1
  for (int t = 0; t < NKT; ++t) {
    const int cur = t & 1;
    s16x8 afn[4];
    if (t + 1 < NKT) {
      // prefetch A(t+1), X(t+1) into registers (latency hides under MFMA)
#pragma unroll
      for (int m = 0; m < 4; ++m)
        afn[m] = ap[(size_t)((pt*8 + wp*4 + m) * NKT + t + 1) * 64 + lane];
      const int kb = (t + 1) * BK;
#pragma unroll
      for (int j = 0; j < 8; ++j) {
        int kk = kb + kg * 8 + j;
        float2 tt; tt.x = 0.f; tt.y = 0.f;
        if (cok && kk < T_SEQ) tt = *(const float2*)(xb + (size_t)kk * C_LEN + cg);
        v[j] = tt;
      }
    }

    // compute from xT[cur]
    s16x8 bf_[4];
#pragma unroll
    for (int n = 0; n < 4; ++n)
      bf_[n] = *(const s16x8*)&xT[cur][(wc*64 + n*16 + l16) * XP + lg * 8];
#pragma unroll
    for (int m = 0; m < 4; ++m)
#pragma unroll
      for (int n = 0; n < 4; ++n)
        acc[m][n] = __builtin_amdgcn_mfma_f32_16x16x32_bf16(
            afc[m], bf_[n], acc[m][n], 0, 0, 0);

    if (t + 1 < NKT) {
      union { s16x8 vec; uint32_t dw[4]; } pa, pb;
#pragma unroll
      for (int h = 0; h < 4; ++h) {
        uint32_t ra, rb;
        asm("v_cvt_pk_bf16_f32 %0, %1, %2" : "=v"(ra) : "v"(v[2*h].x), "v"(v[2*h+1].x));
        asm("v_cvt_pk_bf16_f32 %0, %1, %2" : "=v"(rb) : "v"(v[2*h].y), "v"(v[2*h+1].y));
        pa.dw[h] = ra; pb.dw[h] = rb;
      }
      *(s16x8*)&xT[cur^1][cpair * XP + kg * 8]     = pa.vec;
      *(s16x8*)&xT[cur^1][(cpair+1) * XP + kg * 8] = pb.vec;
#pragma unroll
      for (int m = 0; m < 4; ++m) afc[m] = afn[m];
    }
    __syncthreads();
  }

  // ---- epilogue: bias + relu + masked store (R1-proven traffic) ----
  // C/D layout: row = lg*4 + r (-> p), col = l16 (-> c)
  const size_t ob = (size_t)b * P_LEN * C_LEN;
#pragma unroll
  for (int m = 0; m < 4; ++m) {
    const int pb0 = p0 + wp*64 + m*16 + lg*4;
    float bv[4];
#pragma unroll
    for (int r = 0; r < 4; ++r)
      bv[r] = (pb0 + r < P_LEN) ? bias[pb0 + r] : 0.f;
#pragma unroll
    for (int n = 0; n < 4; ++n) {
      const int cc = c0 + wc*64 + n*16 + l16;
      if (cc < C_LEN) {
#pragma unroll
        for (int r = 0; r < 4; ++r) {
          if (pb0 + r < P_LEN) {
            float vv = acc[m][n][r] + bv[r];
            out[ob + (size_t)(pb0 + r) * C_LEN + cc] = fmaxf(vv, 0.f);
          }
        }
      }
    }
  }
}

extern "C" void kernel_launch(void* const* d_in, const int* in_sizes, int n_in,
                              void* d_out, int out_size, void* d_ws, size_t ws_size,
                              hipStream_t stream) {
  (void)in_sizes; (void)n_in; (void)out_size; (void)ws_size;
  const float* x  = (const float*)d_in[0];
  const float* Ws = (const float*)d_in[1];
  const float* bs = (const float*)d_in[2];
  const float* Wt = (const float*)d_in[3];
  const float* bt = (const float*)d_in[4];
  float* out = (float*)d_out;

  // ws: Apack (48*11 blocks * 1KB = 540672 B) then bias (720 f32)
  unsigned short* apack = (unsigned short*)d_ws;
  float* bias = (float*)((char*)d_ws + (size_t)NM16 * NKT * 1024);

  prep_w<<<dim3(768), dim3(64), 0, stream>>>(Ws, bs, Wt, bt, apack, bias);
  gemm_kernel<<<dim3(NB * 14 * 6), dim3(256), 0, stream>>>(x, apack, bias, out);
}

// Round 6
// 307.157 us; speedup vs baseline: 2.1462x; 1.0135x over previous
//
#include <hip/hip_runtime.h>
#include <hip/hip_bf16.h>
#include <stdint.h>

#define T_SEQ 336
#define NKT   11        // K-steps of 32 (tail handled by apack zero-pad + clamped reads)
#define P_LEN 720
#define NM16  48        // 16-row p-blocks in apack (768 rows, zero-padded)
#define C_LEN 1782
#define NB    64
#define BM 128
#define BN 128
#define BK 32

typedef __attribute__((ext_vector_type(4))) float f32x4;
typedef __attribute__((ext_vector_type(8))) short s16x8;

__device__ __forceinline__ unsigned short f2bf(float f) {
  unsigned int u = __builtin_bit_cast(unsigned int, f);
  u += 0x7FFFu + ((u >> 16) & 1u);   // RNE
  return (unsigned short)(u >> 16);
}

// Weff[p,k] = Ws[p,k] + 0.2*sum_{t in win(k)} (Wt-Ws)[p,t], packed in MFMA
// A-fragment order: block m16*NKT+kt holds 64 lanes x 16B; lane lg*16+l16
// carries W[m16*16+l16][kt*32+lg*8+j], j=0..7. Zero-padded p>=720, k>=336.
__global__ __launch_bounds__(64) void prep_w(
    const float* __restrict__ Ws, const float* __restrict__ bs,
    const float* __restrict__ Wt, const float* __restrict__ bt,
    unsigned short* __restrict__ apack, float* __restrict__ bias) {
  const int p   = blockIdx.x;          // 0..767
  const int tid = threadIdx.x;         // 0..63
  if (tid < NKT * 4) {
    const int kt = tid >> 2;
    const int lg = tid & 3;
    const float* wsr = Ws + (size_t)p * T_SEQ;
    const float* wtr = Wt + (size_t)p * T_SEQ;
    union { s16x8 v; unsigned short u[8]; } pk;
#pragma unroll
    for (int j = 0; j < 8; ++j) {
      const int k = kt * 32 + lg * 8 + j;
      float val = 0.f;
      if (p < P_LEN && k < T_SEQ) {
        float d;
        if (k == 0) {
          d = 3.f*(wtr[0]-wsr[0]) + 2.f*(wtr[1]-wsr[1]) + (wtr[2]-wsr[2]);
        } else if (k == T_SEQ-1) {
          d = 3.f*(wtr[T_SEQ-1]-wsr[T_SEQ-1]) + 2.f*(wtr[T_SEQ-2]-wsr[T_SEQ-2])
              + (wtr[T_SEQ-3]-wsr[T_SEQ-3]);
        } else {
          int lo = (k-2 < 0) ? 0 : k-2;
          int hi = (k+2 > T_SEQ-1) ? T_SEQ-1 : k+2;
          d = 0.f;
          for (int t = lo; t <= hi; ++t) d += wtr[t]-wsr[t];
        }
        val = wsr[k] + 0.2f*d;
      }
      pk.u[j] = f2bf(val);
    }
    const int m16 = p >> 4;
    const int l16 = p & 15;
    *(s16x8*)&apack[(size_t)(((m16*NKT + kt) * 64) + lg*16 + l16) * 8] = pk.v;
  }
  if (tid == 0 && p < P_LEN) bias[p] = bs[p] + bt[p];
}

// O[b,p,c] = relu( sum_k Weff[p,k] * X[b,k,c] + bias[p] )
// 128x128 tile, 4 waves (2x2). Counted-vmcnt pipeline (T3+T4):
//   X tiles staged as RAW fp32 via global_load_lds(size=4) into a 4-deep LDS
//   ring; raw s_barrier + hand-counted s_waitcnt vmcnt(N) keep tiles t+1,t+2
//   in flight ACROSS barriers (never vmcnt(0) in the loop).
//   fp32->bf16 convert happens at fragment-read time (ds_read + cvt_pk).
//   A-fragments register-resident from L2-hot packed Weff.
// LDS col-swizzle: dword (krow,col) holds x[k0+krow][c0 + (col ^ ((krow>>3)<<4))]
// -> fragment ds_reads are 2-way-conflict only (free).
__global__ __launch_bounds__(256) void gemm_kernel(
    const float* __restrict__ x, const unsigned short* __restrict__ apack,
    const float* __restrict__ bias, float* __restrict__ out) {
  __shared__ float xs[4][BK * BN];   // 4 x 16 KB fp32 ring

  // XCD swizzle: each XCD gets 8 consecutive b; within XCD, p-tiles fastest
  const int bid = blockIdx.x;
  const int w   = (bid & 7) * 672 + (bid >> 3);   // 5376 = 8*672, bijective
  const int b   = w / 84;
  const int rem = w % 84;
  const int ct  = rem / 6;
  const int pt  = rem % 6;
  const int p0  = pt * BM;
  const int c0  = ct * BN;

  const int tid  = threadIdx.x;
  const int lane = tid & 63;
  const int wid  = tid >> 6;      // 0..3
  const int wp   = wid >> 1;
  const int wc   = wid & 1;
  const int l16  = lane & 15;
  const int lg   = lane >> 4;
  const int pt8w = pt * 8 + wp * 4;

  const float* xb = x + (size_t)b * T_SEQ * C_LEN;
  const s16x8* ap = (const s16x8*)apack;

  // Staging: wave wid owns tile rows wid*8..wid*8+7 (swz = wid<<4, constant).
  // gll instr q (0..15): krow = wid*8 + (q>>1), col = (q&1)*64 + (lane^swz).
  const int cswz = lane ^ (wid << 4);                  // in [0,64)
  int coff0 = c0 + cswz;       if (coff0 > C_LEN-1) coff0 = C_LEN-1;
  int coff1 = c0 + 64 + cswz;  if (coff1 > C_LEN-1) coff1 = C_LEN-1;

  f32x4 acc[4][4] = {};
  s16x8 afc[4];

#define STAGE(T, BUF)                                                          \
  {                                                                            \
    const int k0_ = (T) * BK;                                                  \
    _Pragma("unroll")                                                          \
    for (int q = 0; q < 16; ++q) {                                             \
      int krow_ = k0_ + wid * 8 + (q >> 1);                                    \
      if (krow_ > T_SEQ - 1) krow_ = T_SEQ - 1;  /* apack zeros nullify */     \
      const float* src_ = xb + (size_t)krow_ * C_LEN + ((q & 1) ? coff1 : coff0); \
      float* dst_ = &xs[BUF][(wid * 16 + q) * 64];                             \
      __builtin_amdgcn_global_load_lds(                                        \
          (const __attribute__((address_space(1))) unsigned int*)src_,         \
          (__attribute__((address_space(3))) unsigned int*)dst_, 4, 0, 0);     \
    }                                                                          \
  }

#define COMPUTE(T)                                                             \
  {                                                                            \
    const float* xbuf_ = &xs[(T) & 3][0];                                      \
    s16x8 bfr_[4];                                                             \
    _Pragma("unroll")                                                          \
    for (int n = 0; n < 4; ++n) {                                              \
      const int colr_ = (wc * 64 + n * 16 + l16) ^ (lg << 4);                  \
      float f_[8];                                                             \
      _Pragma("unroll")                                                        \
      for (int j = 0; j < 8; ++j)                                              \
        f_[j] = xbuf_[(lg * 8 + j) * BN + colr_];                              \
      union { s16x8 v; uint32_t dw[4]; } bu_;                                  \
      _Pragma("unroll")                                                        \
      for (int h = 0; h < 4; ++h) {                                            \
        uint32_t r_;                                                           \
        asm("v_cvt_pk_bf16_f32 %0, %1, %2"                                     \
            : "=v"(r_) : "v"(f_[2*h]), "v"(f_[2*h+1]));                        \
        bu_.dw[h] = r_;                                                        \
      }                                                                        \
      bfr_[n] = bu_.v;                                                         \
    }                                                                          \
    __builtin_amdgcn_s_setprio(1);                                             \
    _Pragma("unroll")                                                          \
    for (int m = 0; m < 4; ++m)                                                \
      _Pragma("unroll")                                                        \
      for (int n = 0; n < 4; ++n)                                              \
        acc[m][n] = __builtin_amdgcn_mfma_f32_16x16x32_bf16(                   \
            afc[m], bfr_[n], acc[m][n], 0, 0, 0);                              \
    __builtin_amdgcn_s_setprio(0);                                             \
  }

  // Step T: [A(T+1) prefetch][gll X(T+2)][wait vmcnt(VM)][barrier][compute T].
  // Per-wave vmem FIFO (asm memory clobbers fence A-loads & glls in place):
  //   newer-than-X(t) = A(t)4 + X(t+1)16 + A(t+1)4 + X(t+2)16 = 40 (steady).
  //   t=0: A(0) is OLDER than X(0) -> 36.  t=9: 24.  t=10: 4.
#define GSTEP(T, VMSTR)                                                        \
  {                                                                            \
    s16x8 afn_[4];                                                             \
    if ((T) + 1 < NKT) {                                                       \
      _Pragma("unroll")                                                        \
      for (int m = 0; m < 4; ++m)                                              \
        afn_[m] = ap[(size_t)((pt8w + m) * NKT + (T) + 1) * 64 + lane];        \
    }                                                                          \
    if ((T) + 2 < NKT) STAGE((T) + 2, ((T) + 2) & 3);                          \
    asm volatile("s_waitcnt vmcnt(" VMSTR ")" ::: "memory");                   \
    __builtin_amdgcn_s_barrier();                                              \
    __builtin_amdgcn_sched_barrier(0);                                         \
    COMPUTE(T);                                                                \
    if ((T) + 1 < NKT) {                                                       \
      _Pragma("unroll")                                                        \
      for (int m = 0; m < 4; ++m) afc[m] = afn_[m];                            \
    }                                                                          \
  }

  // ---- prologue: A(0) regs + stage X(0), X(1) ----
#pragma unroll
  for (int m = 0; m < 4; ++m)
    afc[m] = ap[(size_t)((pt8w + m) * NKT) * 64 + lane];
  STAGE(0, 0);
  STAGE(1, 1);

  GSTEP(0, "36");
#pragma unroll 1
  for (int t = 1; t <= 8; ++t) GSTEP(t, "40");
  GSTEP(9, "24");
  GSTEP(10, "4");

#undef GSTEP
#undef COMPUTE
#undef STAGE

  // ---- epilogue: bias + relu + masked store ----
  // C/D layout: row = lg*4 + r (-> p), col = l16 (-> c)
  const size_t ob = (size_t)b * P_LEN * C_LEN;
#pragma unroll
  for (int m = 0; m < 4; ++m) {
    const int pb0 = p0 + wp*64 + m*16 + lg*4;
    float bv[4];
#pragma unroll
    for (int r = 0; r < 4; ++r)
      bv[r] = (pb0 + r < P_LEN) ? bias[pb0 + r] : 0.f;
#pragma unroll
    for (int n = 0; n < 4; ++n) {
      const int cc = c0 + wc*64 + n*16 + l16;
      if (cc < C_LEN) {
#pragma unroll
        for (int r = 0; r < 4; ++r) {
          if (pb0 + r < P_LEN) {
            float vv = acc[m][n][r] + bv[r];
            out[ob + (size_t)(pb0 + r) * C_LEN + cc] = fmaxf(vv, 0.f);
          }
        }
      }
    }
  }
}

extern "C" void kernel_launch(void* const* d_in, const int* in_sizes, int n_in,
                              void* d_out, int out_size, void* d_ws, size_t ws_size,
                              hipStream_t stream) {
  (void)in_sizes; (void)n_in; (void)out_size; (void)ws_size;
  const float* x  = (const float*)d_in[0];
  const float* Ws = (const float*)d_in[1];
  const float* bs = (const float*)d_in[2];
  const float* Wt = (const float*)d_in[3];
  const float* bt = (const float*)d_in[4];
  float* out = (float*)d_out;

  // ws: Apack (48*11 blocks * 1KB = 540672 B) then bias (720 f32)
  unsigned short* apack = (unsigned short*)d_ws;
  float* bias = (float*)((char*)d_ws + (size_t)NM16 * NKT * 1024);

  prep_w<<<dim3(768), dim3(64), 0, stream>>>(Ws, bs, Wt, bt, apack, bias);
  gemm_kernel<<<dim3(NB * 14 * 6), dim3(256), 0, stream>>>(x, apack, bias, out);
}

// Round 7
// 304.723 us; speedup vs baseline: 2.1634x; 1.0080x over previous
//
#include <hip/hip_runtime.h>
#include <hip/hip_bf16.h>
#include <stdint.h>

#define T_SEQ 336
#define NKT   11        // K-steps of 32 (336 -> 352; pad nullified by apack zeros)
#define P_LEN 720
#define NM16  48        // 16-row p-blocks in apack (768 rows, zero-padded)
#define C_LEN 1782
#define NB    64
#define NCG   112       // 16-wide c-groups (1782 -> 1792, clamped reads, masked stores)

typedef __attribute__((ext_vector_type(4))) float f32x4;
typedef __attribute__((ext_vector_type(8))) short s16x8;

__device__ __forceinline__ unsigned short f2bf(float f) {
  unsigned int u = __builtin_bit_cast(unsigned int, f);
  u += 0x7FFFu + ((u >> 16) & 1u);   // RNE
  return (unsigned short)(u >> 16);
}

// Weff[p,k] = Ws[p,k] + 0.2*sum_{t in win(k)} (Wt-Ws)[p,t], packed in MFMA
// A-fragment order: block m16*NKT+kt holds 64 lanes x 16B; lane lg*16+l16
// carries W[m16*16+l16][kt*32+lg*8+j], j=0..7. Zero-padded p>=720, k>=336.
__global__ __launch_bounds__(64) void prep_w(
    const float* __restrict__ Ws, const float* __restrict__ bs,
    const float* __restrict__ Wt, const float* __restrict__ bt,
    unsigned short* __restrict__ apack, float* __restrict__ bias) {
  const int p   = blockIdx.x;          // 0..767
  const int tid = threadIdx.x;         // 0..63
  if (tid < NKT * 4) {
    const int kt = tid >> 2;
    const int lg = tid & 3;
    const float* wsr = Ws + (size_t)p * T_SEQ;
    const float* wtr = Wt + (size_t)p * T_SEQ;
    union { s16x8 v; unsigned short u[8]; } pk;
#pragma unroll
    for (int j = 0; j < 8; ++j) {
      const int k = kt * 32 + lg * 8 + j;
      float val = 0.f;
      if (p < P_LEN && k < T_SEQ) {
        float d;
        if (k == 0) {
          d = 3.f*(wtr[0]-wsr[0]) + 2.f*(wtr[1]-wsr[1]) + (wtr[2]-wsr[2]);
        } else if (k == T_SEQ-1) {
          d = 3.f*(wtr[T_SEQ-1]-wsr[T_SEQ-1]) + 2.f*(wtr[T_SEQ-2]-wsr[T_SEQ-2])
              + (wtr[T_SEQ-3]-wsr[T_SEQ-3]);
        } else {
          int lo = (k-2 < 0) ? 0 : k-2;
          int hi = (k+2 > T_SEQ-1) ? T_SEQ-1 : k+2;
          d = 0.f;
          for (int t = lo; t <= hi; ++t) d += wtr[t]-wsr[t];
        }
        val = wsr[k] + 0.2f*d;
      }
      pk.u[j] = f2bf(val);
    }
    const int m16 = p >> 4;
    const int l16 = p & 15;
    *(s16x8*)&apack[(size_t)(((m16*NKT + kt) * 64) + lg*16 + l16) * 8] = pk.v;
  }
  if (tid == 0 && p < P_LEN) bias[p] = bs[p] + bt[p];
}

// Pack x into MFMA B-fragment order: block g=(b*NCG+cg)*NKT+kt holds
// 64 lanes x 16B; lane lg*16+l16 carries x[b][kt*32+lg*8+j][cg*16+l16] bf16.
// Clamped (not zeroed) out-of-range reads: K-pad nullified by apack zeros,
// c-pad lanes masked at the GEMM store.
__global__ __launch_bounds__(256) void prep_x(
    const float* __restrict__ x, unsigned short* __restrict__ bpack) {
  const int tid  = threadIdx.x;
  const int lane = tid & 63;
  const int wid  = tid >> 6;
  const int g    = blockIdx.x * 4 + wid;   // 0..78847
  const int kt   = g % NKT;
  const int r    = g / NKT;
  const int cg   = r % NCG;
  const int b    = r / NCG;
  const int l16  = lane & 15;
  const int lg   = lane >> 4;

  int c = cg * 16 + l16; if (c > C_LEN - 1) c = C_LEN - 1;
  const float* xb = x + (size_t)b * T_SEQ * C_LEN;

  float f[8];
#pragma unroll
  for (int j = 0; j < 8; ++j) {
    int k = kt * 32 + lg * 8 + j; if (k > T_SEQ - 1) k = T_SEQ - 1;
    f[j] = xb[(size_t)k * C_LEN + c];
  }
  union { s16x8 v; uint32_t dw[4]; } bu;
#pragma unroll
  for (int h = 0; h < 4; ++h) {
    uint32_t rr;
    asm("v_cvt_pk_bf16_f32 %0, %1, %2" : "=v"(rr) : "v"(f[2*h]), "v"(f[2*h+1]));
    bu.dw[h] = rr;
  }
  *(s16x8*)&bpack[(size_t)g * 512 + lane * 8] = bu.v;
}

// O[b,p,c] = relu( sum_k Weff[p,k] * X[b,k,c] + bias[p] )
// LDS-free, barrier-free: 4 independent waves per block, each owns a 64x64
// tile. Per K-step per wave: 4 A-dwordx4 + 4 B-dwordx4 (both fragment-packed,
// fully coalesced, L2/L3-hot) + 16 MFMA; explicit 1-step register lookahead.
template <bool PACKED>
__global__ __launch_bounds__(256) void gemm_kernel(
    const float* __restrict__ x, const unsigned short* __restrict__ apack,
    const unsigned short* __restrict__ bpack, const float* __restrict__ bias,
    float* __restrict__ out) {
  // XCD swizzle: each XCD gets 8 consecutive b; within XCD, p-tiles fastest
  const int bid = blockIdx.x;
  const int w   = (bid & 7) * 672 + (bid >> 3);   // 5376 = 8*672, bijective
  const int b   = w / 84;
  const int rem = w % 84;
  const int ct  = rem / 6;
  const int pt  = rem % 6;
  const int p0  = pt * 128;
  const int c0  = ct * 128;

  const int tid  = threadIdx.x;
  const int lane = tid & 63;
  const int wid  = tid >> 6;
  const int wp   = wid >> 1;
  const int wc   = wid & 1;
  const int l16  = lane & 15;
  const int lg   = lane >> 4;

  const s16x8* ap = (const s16x8*)apack;
  const s16x8* bp = (const s16x8*)bpack;
  const size_t abase = (size_t)(pt * 8 + wp * 4) * NKT;          // m16-block base
  const size_t bbase = ((size_t)b * NCG + ct * 8 + wc * 4) * NKT; // cg-block base

  auto loadA = [&](int m, int kt) -> s16x8 {
    return ap[(abase + (size_t)m * NKT + kt) * 64 + lane];
  };
  auto loadB = [&](int n, int kt) -> s16x8 {
    if constexpr (PACKED) {
      return bp[(bbase + (size_t)n * NKT + kt) * 64 + lane];
    } else {
      int c = c0 + wc * 64 + n * 16 + l16; if (c > C_LEN - 1) c = C_LEN - 1;
      const float* xb = x + (size_t)b * T_SEQ * C_LEN;
      float f[8];
#pragma unroll
      for (int j = 0; j < 8; ++j) {
        int k = kt * 32 + lg * 8 + j; if (k > T_SEQ - 1) k = T_SEQ - 1;
        f[j] = xb[(size_t)k * C_LEN + c];
      }
      union { s16x8 v; uint32_t dw[4]; } bu;
#pragma unroll
      for (int h = 0; h < 4; ++h) {
        uint32_t rr;
        asm("v_cvt_pk_bf16_f32 %0, %1, %2" : "=v"(rr) : "v"(f[2*h]), "v"(f[2*h+1]));
        bu.dw[h] = rr;
      }
      return bu.v;
    }
  };

  f32x4 acc[4][4] = {};
  s16x8 a0[4], b0[4];
#pragma unroll
  for (int m = 0; m < 4; ++m) a0[m] = loadA(m, 0);
#pragma unroll
  for (int n = 0; n < 4; ++n) b0[n] = loadB(n, 0);

#pragma unroll
  for (int kt = 0; kt < NKT; ++kt) {
    s16x8 a1[4], b1[4];
    if (kt + 1 < NKT) {
#pragma unroll
      for (int m = 0; m < 4; ++m) a1[m] = loadA(m, kt + 1);
#pragma unroll
      for (int n = 0; n < 4; ++n) b1[n] = loadB(n, kt + 1);
    }
#pragma unroll
    for (int m = 0; m < 4; ++m)
#pragma unroll
      for (int n = 0; n < 4; ++n)
        acc[m][n] = __builtin_amdgcn_mfma_f32_16x16x32_bf16(
            a0[m], b0[n], acc[m][n], 0, 0, 0);
    if (kt + 1 < NKT) {
#pragma unroll
      for (int m = 0; m < 4; ++m) a0[m] = a1[m];
#pragma unroll
      for (int n = 0; n < 4; ++n) b0[n] = b1[n];
    }
  }

  // epilogue: bias + relu + masked store. C/D: row = lg*4 + r, col = l16
  const size_t ob = (size_t)b * P_LEN * C_LEN;
#pragma unroll
  for (int m = 0; m < 4; ++m) {
    const int pb0 = p0 + wp * 64 + m * 16 + lg * 4;
    float bv[4];
#pragma unroll
    for (int r = 0; r < 4; ++r)
      bv[r] = (pb0 + r < P_LEN) ? bias[pb0 + r] : 0.f;
#pragma unroll
    for (int n = 0; n < 4; ++n) {
      const int cc = c0 + wc * 64 + n * 16 + l16;
      if (cc < C_LEN) {
#pragma unroll
        for (int r = 0; r < 4; ++r) {
          if (pb0 + r < P_LEN) {
            float vv = acc[m][n][r] + bv[r];
            out[ob + (size_t)(pb0 + r) * C_LEN + cc] = fmaxf(vv, 0.f);
          }
        }
      }
    }
  }
}

extern "C" void kernel_launch(void* const* d_in, const int* in_sizes, int n_in,
                              void* d_out, int out_size, void* d_ws, size_t ws_size,
                              hipStream_t stream) {
  (void)in_sizes; (void)n_in; (void)out_size;
  const float* x  = (const float*)d_in[0];
  const float* Ws = (const float*)d_in[1];
  const float* bs = (const float*)d_in[2];
  const float* Wt = (const float*)d_in[3];
  const float* bt = (const float*)d_in[4];
  float* out = (float*)d_out;

  // ws layout: apack 540672 B | bias 2880 B (+pad) | bpack 78848 KiB
  unsigned short* apack = (unsigned short*)d_ws;
  float* biasp = (float*)((char*)d_ws + 540672);
  unsigned short* bpack = (unsigned short*)((char*)d_ws + 544768);
  const size_t need = 544768 + (size_t)NB * NCG * NKT * 1024;

  prep_w<<<dim3(768), dim3(64), 0, stream>>>(Ws, bs, Wt, bt, apack, biasp);
  if (ws_size >= need) {
    prep_x<<<dim3(NB * NCG * NKT / 4), dim3(256), 0, stream>>>(x, bpack);
    gemm_kernel<true><<<dim3(NB * 84), dim3(256), 0, stream>>>(
        x, apack, bpack, biasp, out);
  } else {
    gemm_kernel<false><<<dim3(NB * 84), dim3(256), 0, stream>>>(
        x, apack, apack /*unused*/, biasp, out);
  }
}